// Round 1
// baseline (540.490 us; speedup 1.0000x reference)
//
#include <hip/hip_runtime.h>
#include <math.h>

// Problem: out[b,i,j] = (i==j) + sum_k F[i,k]F[j,k] + s[b]*x[b,i]*x[b,j]
//   with F = metric_factors[chart], s[b] = 1 - sum_k softmax(x[b])_k^2
// B=2048, D=256, fp32. Write-BW bound: 512 MiB output.

#define DIM 256
#define BATCH 2048

// ---------------- kernel 1: base = I + F F^T  (D x D) ----------------
// grid (8,8), block (16,16); each block computes a 32x32 tile of base,
// each thread a 2x2 micro-tile. LDS-tiled over K.
__global__ __launch_bounds__(256) void base_kernel(const float* __restrict__ mf,
                                                   const int* __restrict__ chart,
                                                   float* __restrict__ base) {
    const float* F = mf + (size_t)chart[0] * DIM * DIM;
    __shared__ float As[32][33];
    __shared__ float Bs[32][33];
    const int tx = threadIdx.x, ty = threadIdx.y;
    const int tid = ty * 16 + tx;           // 0..255
    const int i0 = blockIdx.y * 32, j0 = blockIdx.x * 32;
    float acc00 = 0.f, acc01 = 0.f, acc10 = 0.f, acc11 = 0.f;

    const int lrow = tid >> 3;              // 0..31
    const int lc4  = (tid & 7) * 4;         // 0,4,...,28

    for (int k0 = 0; k0 < DIM; k0 += 32) {
        float4 a = *(const float4*)(F + (size_t)(i0 + lrow) * DIM + k0 + lc4);
        float4 b = *(const float4*)(F + (size_t)(j0 + lrow) * DIM + k0 + lc4);
        As[lrow][lc4 + 0] = a.x; As[lrow][lc4 + 1] = a.y;
        As[lrow][lc4 + 2] = a.z; As[lrow][lc4 + 3] = a.w;
        Bs[lrow][lc4 + 0] = b.x; Bs[lrow][lc4 + 1] = b.y;
        Bs[lrow][lc4 + 2] = b.z; Bs[lrow][lc4 + 3] = b.w;
        __syncthreads();
        #pragma unroll
        for (int kk = 0; kk < 32; ++kk) {
            float a0 = As[ty * 2 + 0][kk];
            float a1 = As[ty * 2 + 1][kk];
            float b0 = Bs[tx * 2 + 0][kk];
            float b1 = Bs[tx * 2 + 1][kk];
            acc00 += a0 * b0; acc01 += a0 * b1;
            acc10 += a1 * b0; acc11 += a1 * b1;
        }
        __syncthreads();
    }
    const int i = i0 + ty * 2, j = j0 + tx * 2;
    base[(size_t)(i + 0) * DIM + (j + 0)] = acc00 + ((i + 0) == (j + 0) ? 1.0f : 0.0f);
    base[(size_t)(i + 0) * DIM + (j + 1)] = acc01 + ((i + 0) == (j + 1) ? 1.0f : 0.0f);
    base[(size_t)(i + 1) * DIM + (j + 0)] = acc10 + ((i + 1) == (j + 0) ? 1.0f : 0.0f);
    base[(size_t)(i + 1) * DIM + (j + 1)] = acc11 + ((i + 1) == (j + 1) ? 1.0f : 0.0f);
}

// ---------------- kernel 2: fused softmax-scale + outer-product write --------
// One block (256 threads) per batch row b. x[b,:] staged in LDS; s[b]
// computed in-block; then 64 iterations of coalesced float4 stores.
__global__ __launch_bounds__(256) void main_kernel(const float* __restrict__ x,
                                                   const float* __restrict__ base,
                                                   float* __restrict__ out) {
    const int b = blockIdx.x;
    const int t = threadIdx.x;            // 0..255
    __shared__ float xs[DIM];
    __shared__ float redm[4], redz[4], redq[4];
    __shared__ float bmax_sh, s_sh;

    const float xv = x[(size_t)b * DIM + t];
    xs[t] = xv;

    // block max (stability)
    float m = xv;
    #pragma unroll
    for (int off = 32; off; off >>= 1) m = fmaxf(m, __shfl_xor(m, off));
    const int wave = t >> 6;
    if ((t & 63) == 0) redm[wave] = m;
    __syncthreads();
    if (t == 0) bmax_sh = fmaxf(fmaxf(redm[0], redm[1]), fmaxf(redm[2], redm[3]));
    __syncthreads();
    m = bmax_sh;

    // Z = sum e, Q = sum e^2 ; s = 1 - Q/Z^2
    const float e = __expf(xv - m);
    float z = e, q = e * e;
    #pragma unroll
    for (int off = 32; off; off >>= 1) { z += __shfl_xor(z, off); q += __shfl_xor(q, off); }
    if ((t & 63) == 0) { redz[wave] = z; redq[wave] = q; }
    __syncthreads();
    if (t == 0) {
        float Z = redz[0] + redz[1] + redz[2] + redz[3];
        float Q = redq[0] + redq[1] + redq[2] + redq[3];
        s_sh = 1.0f - Q / (Z * Z);
    }
    __syncthreads();
    const float s = s_sh;

    const float4* xs4   = (const float4*)xs;
    const float4* base4 = (const float4*)base;
    float4* out4 = (float4*)(out + (size_t)b * DIM * DIM);

    const int j4   = t & 63;   // float4 column index, contiguous within wave
    const int irow = t >> 6;   // 0..3
    const float4 xj = xs4[j4];

    #pragma unroll 4
    for (int it = 0; it < 64; ++it) {
        const int i = it * 4 + irow;
        const float sx = s * xs[i];
        const float4 bb = base4[i * 64 + j4];
        float4 v;
        v.x = bb.x + sx * xj.x;
        v.y = bb.y + sx * xj.y;
        v.z = bb.z + sx * xj.z;
        v.w = bb.w + sx * xj.w;
        out4[i * 64 + j4] = v;
    }
}

extern "C" void kernel_launch(void* const* d_in, const int* in_sizes, int n_in,
                              void* d_out, int out_size, void* d_ws, size_t ws_size,
                              hipStream_t stream) {
    const float* x  = (const float*)d_in[0];               // [2048, 256]
    const float* mf = (const float*)d_in[1];               // [4, 256, 256]
    const int* chart = (const int*)d_in[2];                // scalar
    float* out  = (float*)d_out;                           // [2048, 256, 256]
    float* base = (float*)d_ws;                            // 256*256 floats = 256 KiB

    base_kernel<<<dim3(8, 8), dim3(16, 16), 0, stream>>>(mf, chart, base);
    main_kernel<<<dim3(BATCH), dim3(256), 0, stream>>>(x, base, out);
}